// Round 9
// baseline (193.652 us; speedup 1.0000x reference)
//
#include <hip/hip_runtime.h>
#include <hip/hip_bf16.h>

// Problem constants (from reference)
#define V 50000
#define D 128
#define B 2048
#define P 20

// Stage-1: x[B][D] = inputs[B][V] @ W_emb[D][V]^T, split-K, slice-ring pipeline
#define BM 256
#define NSPLIT 32               // 8 XCDs x 4 splits; grid = 8 m-tiles x 32 = 256 = 1 block/CU
#define KC 1568                 // 49 sub-steps of 32 k
#define NSUB 49
#define VPAD (NSPLIT * KC)      // 50176 zero-padded bf16 W
#define NMT (B / BM)            // 8

typedef float  f32x4  __attribute__((ext_vector_type(4)));
typedef short  bf16x8 __attribute__((ext_vector_type(8)));
typedef unsigned int uint4v __attribute__((ext_vector_type(4)));

__device__ __forceinline__ unsigned int pk2(float a, float b) {
    return (__float_as_uint(b) & 0xFFFF0000u) | (__float_as_uint(a) >> 16);
}
__device__ __forceinline__ unsigned short f2bf(float f) {
    unsigned int u = __float_as_uint(f);
    return (unsigned short)((u + 0x7FFFu + ((u >> 16) & 1u)) >> 16);
}
__device__ __forceinline__ bf16x8 pack8(f32x4 lo, f32x4 hi) {
    union { uint4v u; bf16x8 h; } r;
    r.u.x = pk2(lo[0], lo[1]); r.u.y = pk2(lo[2], lo[3]);
    r.u.z = pk2(hi[0], hi[1]); r.u.w = pk2(hi[2], hi[3]);
    return r.h;
}

// ---------------- pre-pass: W_emb fp32 [D][V] -> bf16 [D][VPAD], zero pad ----------------
__global__ __launch_bounds__(256)
void w2v_wcast(const float* __restrict__ Wemb, unsigned short* __restrict__ Wb) {
    const size_t t = (size_t)blockIdx.x * 256 + threadIdx.x;   // grid 3136 exact
    const size_t base = t * 8;
    const int d = (int)(base / VPAD);
    const int k = (int)(base % VPAD);
    uint4v u = {0u, 0u, 0u, 0u};
    if (k + 8 <= V) {
        const f32x4* src = reinterpret_cast<const f32x4*>(Wemb + (size_t)d * V + k);
        f32x4 v0 = src[0], v1 = src[1];
        u.x = pk2(v0[0], v0[1]); u.y = pk2(v0[2], v0[3]);
        u.z = pk2(v1[0], v1[1]); u.w = pk2(v1[2], v1[3]);
    }
    *reinterpret_cast<uint4v*>(Wb + (size_t)d * VPAD + k) = u;
}

// ---------------- stage 1: slice-ring split-K GEMM ----------------
// LDS = 128 KB ring: [4 row-groups][8 k-slices] tiles of [64 rows][32 k] bf16 (4 KB).
// Per sub-step u: ds_write A batch (loaded u-1, 512 B/row visits) -> load next A batch
// -> load next W frags (direct global) -> 16 MFMA -> lgkm barrier. Strict FIFO =>
// compiler emits counted vmcnt (no drain); A prefetched 8 subs ahead via the ring.
template<int FAST>
__global__ __launch_bounds__(512, 2)
void w2v_gemm(const float* __restrict__ Ain, const void* __restrict__ Wsrc,
              void* __restrict__ part) {
    __shared__ uint4v smem4[8192];         // 128 KB
    char* smem = (char*)smem4;

    const int i   = blockIdx.x;            // 0..255
    const int xcd = i & 7;
    const int q   = i >> 3;                // 0..31
    const int s   = xcd * 4 + (q >> 3);    // 0..31 (4 splits per XCD)
    const int mt  = q & 7;
    const int m0  = mt * BM;
    const int k0  = s * KC;
    const int k1  = (k0 + KC < V) ? (k0 + KC) : V;

    const int tid  = threadIdx.x;
    const int lane = tid & 63;
    const int wid  = tid >> 6;
    const int w32  = wid * 32;
    const int fr   = lane & 15;
    const int kg4  = lane >> 4;

    f32x4 acc[2][8] = {};

    // A staging geometry: batch = [64 rows of group g][128 k]; thread: row tid>>3,
    // floats [akt*16, +16) -> one 32-k slice half (512 B/row per batch, page-friendly)
    const int arow = tid >> 3;             // 0..63
    const int akt  = tid & 7;
    const unsigned short* Wb = (const unsigned short*)Wsrc;
    const float*          Wf = (const float*)Wsrc;

    f32x4  aRA[4], aRB[4];
    bf16x8 wfA[8], wfB[8];

    auto loadA = [&](f32x4* aR, int g, int Kb) {
#pragma unroll
        for (int c = 0; c < 4; ++c) {
            const int kg = Kb + akt * 16 + c * 4;
            f32x4 v = {0.f, 0.f, 0.f, 0.f};
            if (kg + 4 <= k1)
                v = *reinterpret_cast<const f32x4*>(Ain + (size_t)(m0 + g * 64 + arow) * V + kg);
            aR[c] = v;
        }
    };
    auto writeA = [&](const f32x4* aR, int g, int Kb) {
        const int sl = ((Kb >> 5) + (akt >> 1)) & 7;             // k-slice of thread's 16 floats
        char* t = smem + (g * 8 + sl) * 4096 + arow * 64;
#pragma unroll
        for (int h = 0; h < 2; ++h) {
            uint4v u;
            u.x = pk2(aR[h*2][0], aR[h*2][1]);   u.y = pk2(aR[h*2][2], aR[h*2][3]);
            u.z = pk2(aR[h*2+1][0], aR[h*2+1][1]); u.w = pk2(aR[h*2+1][2], aR[h*2+1][3]);
            const int c2 = (akt & 1) * 2 + h;                    // chunk 0..3 in tile row
            *reinterpret_cast<uint4v*>(t + ((c2 ^ (arow & 3)) << 4)) = u;
        }
    };
    auto loadW = [&](bf16x8* wf, int kw) {
        if (FAST) {
#pragma unroll
            for (int n = 0; n < 8; ++n)
                wf[n] = *reinterpret_cast<const bf16x8*>(Wb + (size_t)(n * 16 + fr) * VPAD + kw + kg4 * 8);
        } else {
#pragma unroll
            for (int n = 0; n < 8; ++n) {
                const int kg = kw + kg4 * 8;
                f32x4 lo = {0,0,0,0}, hi = {0,0,0,0};
                if (kg + 8 <= V) {
                    const f32x4* p = reinterpret_cast<const f32x4*>(Wf + (size_t)(n * 16 + fr) * V + kg);
                    lo = p[0]; hi = p[1];
                }
                wf[n] = pack8(lo, hi);
            }
        }
    };
    auto compute = [&](const bf16x8* wf, int u) {
        const int sl = u & 7;
        bf16x8 af[2];
#pragma unroll
        for (int m = 0; m < 2; ++m) {
            const int rr = w32 + m * 16 + fr;
            const int g = rr >> 6, rin = rr & 63;
            af[m] = *reinterpret_cast<const bf16x8*>(
                smem + (g * 8 + sl) * 4096 + rin * 64 + ((kg4 ^ (rin & 3)) << 4));
        }
#pragma unroll
        for (int n = 0; n < 8; ++n) {
            acc[0][n] = __builtin_amdgcn_mfma_f32_16x16x32_bf16(af[0], wf[n], acc[0][n], 0, 0, 0);
            acc[1][n] = __builtin_amdgcn_mfma_f32_16x16x32_bf16(af[1], wf[n], acc[1][n], 0, 0, 0);
        }
    };
    auto barrier = [&]() {
        asm volatile("s_waitcnt lgkmcnt(0)" ::: "memory");
        __builtin_amdgcn_s_barrier();
    };

    // ---- prologue: fill ring slices k0..k0+255 (8 batches, 2-deep pipelined) ----
    loadA(aRA, 0, k0);
    loadA(aRB, 1, k0);
#pragma unroll
    for (int b = 0; b < 8; ++b) {
        const int g = b & 3, Kb = k0 + (b >> 2) * 128;
        if (b & 1) { writeA(aRB, g, Kb); if (b + 2 < 8) loadA(aRB, (b + 2) & 3, k0 + ((b + 2) >> 2) * 128); }
        else       { writeA(aRA, g, Kb); if (b + 2 < 8) loadA(aRA, (b + 2) & 3, k0 + ((b + 2) >> 2) * 128); }
    }
    loadA(aRA, 0, k0 + 128);               // u=0's write batch (idempotent overlap)
    loadW(wfA, k0);                        // wf for sub 0
    barrier();

    // ---- main loop: 49 sub-steps, unrolled x2 for static reg parity ----
    auto sub = [&](int u, f32x4* aW, f32x4* aL, bf16x8* wfC, bf16x8* wfL) {
        if (u <= 44) writeA(aW, u & 3, k0 + (u + 4) * 32);
        if (u <= 43) loadA(aL, (u + 1) & 3, k0 + (u + 5) * 32);
        if (u <= 47) loadW(wfL, k0 + (u + 1) * 32);
        compute(wfC, u);
        barrier();
    };
    for (int uu = 0; uu < 48; uu += 2) {
        sub(uu,     aRA, aRB, wfA, wfB);
        sub(uu + 1, aRB, aRA, wfB, wfA);
    }
    sub(48, aRA, aRB, wfA, wfB);

    // ---- epilogue (C/D layout: col = lane&15, row = kg4*4 + jj) ----
    if (!FAST) {
        float* outp = (float*)part;        // fp32 [B][D], atomic accumulate
#pragma unroll
        for (int m = 0; m < 2; ++m) {
            const int r0 = m0 + w32 + m * 16 + kg4 * 4;
#pragma unroll
            for (int n = 0; n < 8; ++n) {
                const int c = n * 16 + fr;
#pragma unroll
                for (int jj = 0; jj < 4; ++jj)
                    atomicAdd(&outp[(size_t)(r0 + jj) * D + c], acc[m][n][jj]);
            }
        }
        return;
    }
    unsigned short* Cs = (unsigned short*)smem;   // [256][128] bf16 = 64 KB
#pragma unroll
    for (int m = 0; m < 2; ++m) {
        const int r0 = w32 + m * 16 + kg4 * 4;
#pragma unroll
        for (int n = 0; n < 8; ++n) {
            const int c = n * 16 + fr;
#pragma unroll
            for (int jj = 0; jj < 4; ++jj)
                Cs[(r0 + jj) * 128 + c] = f2bf(acc[m][n][jj]);
        }
    }
    __syncthreads();
    char* dstb = (char*)part + ((size_t)s * B + m0) * (D * 2);   // [s][b][d] bf16
#pragma unroll
    for (int it = 0; it < 8; ++it) {
        const int off = (it * 512 + tid) * 16;                   // 64 KB coalesced
        uint4v v = *reinterpret_cast<const uint4v*>(smem + off);
        *reinterpret_cast<uint4v*>(dstb + off) = v;
    }
}

// ---------------- stage 2: reduce splits + gathered cls dots + BCE + mean ----------------
__global__ __launch_bounds__(256)
void w2v_loss(const void* __restrict__ part, int part_bf16,
              const float* __restrict__ Wcls, const int* __restrict__ pathIdx,
              const float* __restrict__ codes, const float* __restrict__ mask,
              float* __restrict__ out) {
    const int lane = threadIdx.x & 63;
    const int wid  = threadIdx.x >> 6;
    const int b    = blockIdx.x * 4 + wid;     // one wave per sample

    float x0 = 0.f, x1 = 0.f;                  // x[b][2*lane], x[b][2*lane+1]
    if (part_bf16) {
        const unsigned* pb = (const unsigned*)part;   // 64 u32 per [s][b] row
#pragma unroll 8
        for (int s = 0; s < NSPLIT; ++s) {
            unsigned u = pb[((size_t)s * B + b) * 64 + lane];
            x0 += __uint_as_float(u << 16);
            x1 += __uint_as_float(u & 0xFFFF0000u);
        }
    } else {
        const float* pf = (const float*)part;         // [B][D] fp32, pre-reduced
        const float2 v = *reinterpret_cast<const float2*>(&pf[(size_t)b * D + lane * 2]);
        x0 = v.x; x1 = v.y;
    }

    float lsum = 0.f, msum = 0.f;
#pragma unroll
    for (int p = 0; p < P; ++p) {
        int node = pathIdx[b * P + p];
        const float2 w = *reinterpret_cast<const float2*>(&Wcls[(size_t)node * D + lane * 2]);
        float d = x0 * w.x + x1 * w.y;
#pragma unroll
        for (int off = 1; off < 64; off <<= 1)
            d += __shfl_xor(d, off, 64);
        float t  = codes[b * P + p];
        float mm = mask[b * P + p];
        float loss = fmaxf(d, 0.f) - d * t + log1pf(__expf(-fabsf(d)));
        lsum += loss * mm;
        msum += mm;
    }
    float per = (msum > 0.f) ? (lsum / msum) : 0.f;

    __shared__ float wsum[4];
    if (lane == 0) wsum[wid] = per;
    __syncthreads();
    if (threadIdx.x == 0) {
        float ssum = wsum[0] + wsum[1] + wsum[2] + wsum[3];
        atomicAdd(out, ssum * (1.0f / (float)B));
    }
}

extern "C" void kernel_launch(void* const* d_in, const int* in_sizes, int n_in,
                              void* d_out, int out_size, void* d_ws, size_t ws_size,
                              hipStream_t stream) {
    const float* inputs = (const float*)d_in[0];   // [B,V]
    const float* W_emb  = (const float*)d_in[1];   // [D,V]
    const float* W_cls  = (const float*)d_in[2];   // [V,D]
    const int*   path   = (const int*)  d_in[3];   // [B,P]
    const float* codes  = (const float*)d_in[4];   // [B,P]
    const float* mask   = (const float*)d_in[5];   // [B,P]
    float* out = (float*)d_out;

    hipMemsetAsync(d_out, 0, sizeof(float), stream);

    const size_t wb_bytes  = (size_t)D * VPAD * 2;                    // ~12.8 MB
    const size_t part_off  = (wb_bytes + 255) & ~(size_t)255;
    const size_t part_need = part_off + (size_t)NSPLIT * B * D * 2;   // ~29.7 MB

    if (ws_size >= part_need) {
        unsigned short* Wb = (unsigned short*)d_ws;
        char* partp = (char*)d_ws + part_off;
        w2v_wcast<<<dim3((unsigned)((size_t)D * VPAD / 8 / 256)), dim3(256), 0, stream>>>(W_emb, Wb);
        w2v_gemm<1><<<dim3(NMT * NSPLIT), dim3(512), 0, stream>>>(inputs, Wb, partp);
        w2v_loss<<<dim3(B / 4), dim3(256), 0, stream>>>(partp, 1, W_cls, path, codes, mask, out);
    } else {
        hipMemsetAsync(d_ws, 0, (size_t)B * D * sizeof(float), stream);
        w2v_gemm<0><<<dim3(NMT * NSPLIT), dim3(512), 0, stream>>>(inputs, W_emb, d_ws);
        w2v_loss<<<dim3(B / 4), dim3(256), 0, stream>>>(d_ws, 0, W_cls, path, codes, mask, out);
    }
}

// Round 10
// 170.562 us; speedup vs baseline: 1.1354x; 1.1354x over previous
//
#include <hip/hip_runtime.h>
#include <hip/hip_bf16.h>

// Problem constants (from reference)
#define V 50000
#define D 128
#define B 2048
#define P 20

// Stage-1: x[B][D] = inputs[B][V] @ W_emb[D][V]^T, split-K
#define BM 128
#define NSPLIT 32               // 8 XCDs x 4 splits; grid 16*32 = 512 = exactly 2 blocks/CU
#define KC 1568                 // 49 slices of 32 k per split; 25 steps of 64 k (last half)
#define VPAD (NSPLIT * KC)      // 50176
#define NSLICE (VPAD / 32)      // 1568
#define NMT (B / BM)            // 16

typedef float  f32x4  __attribute__((ext_vector_type(4)));
typedef short  bf16x8 __attribute__((ext_vector_type(8)));
typedef unsigned int uint4v __attribute__((ext_vector_type(4)));

// truncating fp32->bf16 pack of two floats into one u32 (low = a, high = b)
__device__ __forceinline__ unsigned int pk2(float a, float b) {
    return (__float_as_uint(b) & 0xFFFF0000u) | (__float_as_uint(a) >> 16);
}
// RNE fp32->bf16
__device__ __forceinline__ unsigned short f2bf(float f) {
    unsigned int u = __float_as_uint(f);
    return (unsigned short)((u + 0x7FFFu + ((u >> 16) & 1u)) >> 16);
}
__device__ __forceinline__ bf16x8 pack8(f32x4 lo, f32x4 hi) {
    union { uint4v u; bf16x8 h; } r;
    r.u.x = pk2(lo[0], lo[1]); r.u.y = pk2(lo[2], lo[3]);
    r.u.z = pk2(hi[0], hi[1]); r.u.w = pk2(hi[2], hi[3]);
    return r.h;
}
// async global->LDS, 16 B/lane; LDS dest = wave-uniform base (+lane*16 implicit)
__device__ __forceinline__ void gload_lds16(const void* g, void* l) {
    __builtin_amdgcn_global_load_lds(
        (const __attribute__((address_space(1))) unsigned int*)g,
        (__attribute__((address_space(3))) unsigned int*)l, 16, 0, 0);
}

// ---- pre-pass: W_emb fp32 [D][V] -> WTF, MFMA-fragment-ordered bf16 ----
// WTF byte layout: slice ks5 (32 k's), coltile n (16 cols), lane l (col n*16+(l&15),
// k-group (l>>4)*8): off = ks5*8192 + n*1024 + l*16. Zero-padded to VPAD k's.
__global__ __launch_bounds__(256)
void w2v_wcast(const float* __restrict__ Wemb, unsigned short* __restrict__ WTF) {
    __shared__ unsigned short L[128 * 128];        // 32 KB [d][128 k] swizzled chunks
    const int bk = blockIdx.x;                     // 0..391: k-window [bk*128, +128)
    const int t  = threadIdx.x;
    // phase 1: coalesced read (256 B/row halves) + pack -> LDS
    const int d = t >> 1, h = t & 1;
    const float* src = Wemb + (size_t)d * V + bk * 128 + h * 64;
#pragma unroll
    for (int j = 0; j < 8; ++j) {
        const int kg = bk * 128 + h * 64 + j * 8;
        f32x4 v0 = {0,0,0,0}, v1 = {0,0,0,0};
        if (kg + 8 <= V) {                         // V%8==0 -> full or pad
            const f32x4* p = reinterpret_cast<const f32x4*>(src + j * 8);
            v0 = p[0]; v1 = p[1];
        }
        uint4v u;
        u.x = pk2(v0[0], v0[1]); u.y = pk2(v0[2], v0[3]);
        u.z = pk2(v1[0], v1[1]); u.w = pk2(v1[2], v1[3]);
        const int c8 = h * 8 + j;
        *reinterpret_cast<uint4v*>((char*)L + d * 256 + ((c8 ^ (d & 15)) << 4)) = u;
    }
    __syncthreads();
    // phase 2: gather fragments, write 1 KB/wave-instr contiguous
    const int w = t >> 6, l = t & 63;
    const int kg4 = l >> 4, fr = l & 15;
#pragma unroll
    for (int sl = 0; sl < 4; ++sl)
#pragma unroll
        for (int j2 = 0; j2 < 2; ++j2) {
            const int n  = w + j2 * 4;
            const int dd = n * 16 + fr;
            const int c8 = sl * 4 + kg4;
            uint4v u = *reinterpret_cast<const uint4v*>(
                (char*)L + dd * 256 + ((c8 ^ (dd & 15)) << 4));
            *reinterpret_cast<uint4v*>(
                (char*)WTF + ((size_t)(bk * 4 + sl) * 8 + n) * 1024 + l * 16) = u;
        }
}

// ---- stage 1: split-K GEMM. A reg-staged issue-early; W via linear global_load_lds
// from fragment-ordered WTF. 1 raw barrier/step, counted vmcnt(12) (never drains). ----
template<int FAST>
__global__ __launch_bounds__(256, 2)
void w2v_gemm(const float* __restrict__ Ain, const void* __restrict__ Wsrc,
              void* __restrict__ part) {
    __shared__ char smem[65536];   // A dbuf: [0,32K) 2x16K swizzled; W dbuf: [32K,64K) 2x16K linear
    char* Wlds = smem + 32768;

    const int i   = blockIdx.x;            // 0..511
    const int xcd = i & 7;
    const int q   = i >> 3;                // 0..63
    const int s   = xcd * 4 + (q >> 4);    // 0..31 (4 splits/XCD)
    const int mt  = q & 15;
    const int m0  = mt * BM;
    const int k0  = s * KC;
    const int kend = (k0 + KC < V) ? (k0 + KC) : V;
    const int nst  = (kend - k0 + 63) >> 6;        // 25 (s=31: 22)

    const int tid  = threadIdx.x;
    const int lane = tid & 63;
    const int wid  = tid >> 6;
    const int w32  = wid * 32;
    const int fr   = lane & 15;
    const int kg4  = lane >> 4;

    f32x4 acc[2][8] = {};

    // A staging: thread = (row tid>>1, 32-k half tid&1); lane-pairs cover 256 B/row
    const int arow = tid >> 1;
    const int ah   = tid & 1;
    const float* aSrc = Ain + (size_t)(m0 + arow) * V + ah * 32;
    const unsigned short* WT = (const unsigned short*)Wsrc;  // FAST: WTF
    const float*          Wf = (const float*)Wsrc;           // !FAST: fp32 [D][V]

    f32x4 aR[8];
    auto loadA = [&](int ks) {             // exactly 8 loads always (clamp+select)
#pragma unroll
        for (int j = 0; j < 8; ++j) {
            const bool ok = (ks + ah * 32 + j * 4 + 4 <= kend);
            const f32x4* p = reinterpret_cast<const f32x4*>(ok ? (aSrc + ks + j * 4)
                                                               : (aSrc + k0));
            f32x4 v = *p;
            if (!ok) v = f32x4{0.f, 0.f, 0.f, 0.f};
            aR[j] = v;
        }
    };
    auto writeA = [&](int buf) {           // 4 x ds_write_b128, swizzled chunks
        char* base = smem + buf * 16384 + arow * 128;
#pragma unroll
        for (int j2 = 0; j2 < 4; ++j2) {
            uint4v u;
            u.x = pk2(aR[j2*2][0], aR[j2*2][1]);   u.y = pk2(aR[j2*2][2], aR[j2*2][3]);
            u.z = pk2(aR[j2*2+1][0], aR[j2*2+1][1]); u.w = pk2(aR[j2*2+1][2], aR[j2*2+1][3]);
            const int c8 = ah * 4 + j2;
            *reinterpret_cast<uint4v*>(base + ((c8 ^ (arow & 7)) << 4)) = u;
        }
    };
    auto stageW = [&](int buf, int ks5) {  // 4 x gload_lds (1 KB linear each) per wave
#pragma unroll
        for (int j = 0; j < 4; ++j) {
            const int g = wid * 4 + j;     // seg: slice u=g>>3, coltile n=g&7
            const unsigned short* gp = WT + (size_t)(ks5 + (g >> 3)) * 4096
                                          + (g & 7) * 512 + lane * 8;
            gload_lds16(gp, Wlds + buf * 16384 + g * 1024);
        }
    };
    auto computeMicro = [&](int buf, int u) {      // 16 MFMA
        bf16x8 af[2];
#pragma unroll
        for (int m = 0; m < 2; ++m) {
            const int r  = w32 + m * 16 + fr;
            const int c8 = u * 4 + kg4;
            af[m] = *reinterpret_cast<const bf16x8*>(
                smem + buf * 16384 + r * 128 + ((c8 ^ (r & 7)) << 4));
        }
#pragma unroll
        for (int n = 0; n < 8; ++n) {
            const bf16x8 wf = *reinterpret_cast<const bf16x8*>(
                Wlds + buf * 16384 + (u * 8 + n) * 1024 + lane * 16);
            acc[0][n] = __builtin_amdgcn_mfma_f32_16x16x32_bf16(af[0], wf, acc[0][n], 0, 0, 0);
            acc[1][n] = __builtin_amdgcn_mfma_f32_16x16x32_bf16(af[1], wf, acc[1][n], 0, 0, 0);
        }
    };

    if (FAST) {
        loadA(k0);
        stageW(0, s * 49);                 // k0>>5 = s*49
        for (int t = 0; t < nst; ++t) {
            writeA(t & 1);                 // compiler waits A(t) loads (vmcnt(4)) here
            const bool more = (t + 1 < nst);
            if (more) {
                loadA(k0 + (t + 1) * 64);              // 8 vmem, stay in flight
                stageW((t + 1) & 1, s * 49 + (t + 1) * 2);  // 4 vmem, stay in flight
                asm volatile("s_waitcnt vmcnt(12) lgkmcnt(0)" ::: "memory");
            } else {
                asm volatile("s_waitcnt vmcnt(0) lgkmcnt(0)" ::: "memory");
            }
            __builtin_amdgcn_s_barrier();  // raw: 12 newest loads remain airborne
            computeMicro(t & 1, 0);
            computeMicro(t & 1, 1);        // step-24 micro-1: A zeros x next-split W = 0
        }
    } else {
        bf16x8 wfr[8];
        for (int t = 0; t < nst; ++t) {
            const int ks = k0 + t * 64;
            loadA(ks);
            writeA(0);
            __syncthreads();
#pragma unroll
            for (int u = 0; u < 2; ++u) {
#pragma unroll
                for (int n = 0; n < 8; ++n) {
                    const int kg = ks + u * 32 + kg4 * 8;
                    f32x4 lo = {0,0,0,0}, hi = {0,0,0,0};
                    if (kg + 8 <= V) {
                        const f32x4* p = reinterpret_cast<const f32x4*>(
                            Wf + (size_t)(n * 16 + fr) * V + kg);
                        lo = p[0]; hi = p[1];
                    }
                    wfr[n] = pack8(lo, hi);
                }
                bf16x8 af[2];
#pragma unroll
                for (int m = 0; m < 2; ++m) {
                    const int r  = w32 + m * 16 + fr;
                    const int c8 = u * 4 + kg4;
                    af[m] = *reinterpret_cast<const bf16x8*>(
                        smem + r * 128 + ((c8 ^ (r & 7)) << 4));
                }
#pragma unroll
                for (int n = 0; n < 8; ++n) {
                    acc[0][n] = __builtin_amdgcn_mfma_f32_16x16x32_bf16(af[0], wfr[n], acc[0][n], 0, 0, 0);
                    acc[1][n] = __builtin_amdgcn_mfma_f32_16x16x32_bf16(af[1], wfr[n], acc[1][n], 0, 0, 0);
                }
            }
            __syncthreads();
        }
    }

    // ---- epilogue (C/D: col = lane&15, row = kg4*4 + jj) ----
    if (!FAST) {
        float* outp = (float*)part;        // fp32 [B][D] atomic accumulate
#pragma unroll
        for (int m = 0; m < 2; ++m) {
            const int r0 = m0 + w32 + m * 16 + kg4 * 4;
#pragma unroll
            for (int n = 0; n < 8; ++n) {
                const int c = n * 16 + fr;
#pragma unroll
                for (int jj = 0; jj < 4; ++jj)
                    atomicAdd(&outp[(size_t)(r0 + jj) * D + c], acc[m][n][jj]);
            }
        }
        return;
    }
    asm volatile("s_waitcnt lgkmcnt(0)" ::: "memory");
    __builtin_amdgcn_s_barrier();          // all waves done reading LDS bufs
    unsigned short* Cs = (unsigned short*)smem;   // [128][128] bf16 = 32 KB
#pragma unroll
    for (int m = 0; m < 2; ++m) {
        const int r0 = w32 + m * 16 + kg4 * 4;
#pragma unroll
        for (int n = 0; n < 8; ++n) {
            const int c = n * 16 + fr;
#pragma unroll
            for (int jj = 0; jj < 4; ++jj)
                Cs[(r0 + jj) * 128 + c] = f2bf(acc[m][n][jj]);
        }
    }
    __syncthreads();
    char* dstb = (char*)part + ((size_t)s * B + m0) * (D * 2);   // [s][b][d] bf16
#pragma unroll
    for (int it = 0; it < 8; ++it) {
        const int off = (it * 256 + tid) * 16;                   // 32 KB coalesced
        uint4v v = *reinterpret_cast<const uint4v*>((char*)smem + off);
        *reinterpret_cast<uint4v*>(dstb + off) = v;
    }
}

// ---- stage 2: reduce splits + gathered cls dots + BCE + mean ----
__global__ __launch_bounds__(256)
void w2v_loss(const void* __restrict__ part, int part_bf16,
              const float* __restrict__ Wcls, const int* __restrict__ pathIdx,
              const float* __restrict__ codes, const float* __restrict__ mask,
              float* __restrict__ out) {
    const int lane = threadIdx.x & 63;
    const int wid  = threadIdx.x >> 6;
    const int b    = blockIdx.x * 4 + wid;     // one wave per sample

    float x0 = 0.f, x1 = 0.f;                  // x[b][2*lane], x[b][2*lane+1]
    if (part_bf16) {
        const unsigned* pb = (const unsigned*)part;   // 64 u32 per [s][b] row
#pragma unroll 8
        for (int s = 0; s < NSPLIT; ++s) {
            unsigned u = pb[((size_t)s * B + b) * 64 + lane];
            x0 += __uint_as_float(u << 16);
            x1 += __uint_as_float(u & 0xFFFF0000u);
        }
    } else {
        const float* pf = (const float*)part;         // [B][D] fp32, pre-reduced
        const float2 v = *reinterpret_cast<const float2*>(&pf[(size_t)b * D + lane * 2]);
        x0 = v.x; x1 = v.y;
    }

    float lsum = 0.f, msum = 0.f;
#pragma unroll
    for (int p = 0; p < P; ++p) {
        int node = pathIdx[b * P + p];
        const float2 w = *reinterpret_cast<const float2*>(&Wcls[(size_t)node * D + lane * 2]);
        float d = x0 * w.x + x1 * w.y;
#pragma unroll
        for (int off = 1; off < 64; off <<= 1)
            d += __shfl_xor(d, off, 64);
        float t  = codes[b * P + p];
        float mm = mask[b * P + p];
        float loss = fmaxf(d, 0.f) - d * t + log1pf(__expf(-fabsf(d)));
        lsum += loss * mm;
        msum += mm;
    }
    float per = (msum > 0.f) ? (lsum / msum) : 0.f;

    __shared__ float wsum[4];
    if (lane == 0) wsum[wid] = per;
    __syncthreads();
    if (threadIdx.x == 0) {
        float ssum = wsum[0] + wsum[1] + wsum[2] + wsum[3];
        atomicAdd(out, ssum * (1.0f / (float)B));
    }
}

extern "C" void kernel_launch(void* const* d_in, const int* in_sizes, int n_in,
                              void* d_out, int out_size, void* d_ws, size_t ws_size,
                              hipStream_t stream) {
    const float* inputs = (const float*)d_in[0];   // [B,V]
    const float* W_emb  = (const float*)d_in[1];   // [D,V]
    const float* W_cls  = (const float*)d_in[2];   // [V,D]
    const int*   path   = (const int*)  d_in[3];   // [B,P]
    const float* codes  = (const float*)d_in[4];   // [B,P]
    const float* mask   = (const float*)d_in[5];   // [B,P]
    float* out = (float*)d_out;

    hipMemsetAsync(d_out, 0, sizeof(float), stream);

    const size_t wtf_bytes = (size_t)NSLICE * 8192;                   // ~12.8 MB
    const size_t part_off  = (wtf_bytes + 255) & ~(size_t)255;
    const size_t part_need = part_off + (size_t)NSPLIT * B * D * 2;   // ~29.6 MB

    if (ws_size >= part_need) {
        unsigned short* WTF = (unsigned short*)d_ws;
        char* partp = (char*)d_ws + part_off;
        w2v_wcast<<<dim3(VPAD / 128), dim3(256), 0, stream>>>(W_emb, WTF);
        w2v_gemm<1><<<dim3(NMT * NSPLIT), dim3(256), 0, stream>>>(inputs, WTF, partp);
        w2v_loss<<<dim3(B / 4), dim3(256), 0, stream>>>(partp, 1, W_cls, path, codes, mask, out);
    } else {
        hipMemsetAsync(d_ws, 0, (size_t)B * D * sizeof(float), stream);
        w2v_gemm<0><<<dim3(NMT * NSPLIT), dim3(256), 0, stream>>>(inputs, W_emb, d_ws);
        w2v_loss<<<dim3(B / 4), dim3(256), 0, stream>>>(d_ws, 0, W_cls, path, codes, mask, out);
    }
}